// Round 9
// baseline (1557.219 us; speedup 1.0000x reference)
//
#include <hip/hip_runtime.h>
#include <hip/hip_bf16.h>

#define N_NODES 50000
#define N_EDGES 800000
#define R 8
#define NB 30
#define C1 128
#define C2 256
#define C3 512
#define NR (N_NODES * R)
#define BN_EPS 1e-5f
#define ALPHA 0.01f

typedef unsigned short u16;
typedef __attribute__((ext_vector_type(8))) short short8;
typedef __attribute__((ext_vector_type(4))) float floatx4;

static inline unsigned cdivu(long long a, long long b) { return (unsigned)((a + b - 1) / b); }

__device__ __forceinline__ u16 f2bs(float f) {
    __hip_bfloat16 h = __float2bfloat16(f);
    return *reinterpret_cast<u16*>(&h);
}
__device__ __forceinline__ float b2f(u16 u) {
    return __uint_as_float(((unsigned)u) << 16);
}
__device__ __forceinline__ float ldacc(const float* p) { return *p; }
__device__ __forceinline__ float ldacc(const u16* p) { return b2f(*p); }
__device__ __forceinline__ void stv(float* p, float v) { *p = v; }
__device__ __forceinline__ void stv(u16* p, float v) { *p = f2bs(v); }

// async global->LDS, 16B per lane; LDS dest is wave-uniform base + lane*16
__device__ __forceinline__ void gl_lds16(const u16* g, u16* l) {
    __builtin_amdgcn_global_load_lds(
        (const __attribute__((address_space(1))) void*)g,
        (__attribute__((address_space(3))) void*)l, 16, 0, 0);
}

// ---- weight builders: Bt[o][k] bf16, k = [rel-blocks | root] ----
__global__ void k_b1(const float* __restrict__ comp, const float* __restrict__ basis,
                     const float* __restrict__ root, u16* __restrict__ Bt) {
    int t = blockIdx.x * blockDim.x + threadIdx.x;
    if (t >= C2 * 1152) return;
    int o = t % C2, k = t / C2;         // coalesced basis/root reads over o
    float v;
    if (k < R * C1) {
        int r = k >> 7, i = k & 127;
        v = 0.f;
        for (int b = 0; b < NB; ++b)
            v += comp[r * NB + b] * basis[((size_t)b * C1 + i) * C2 + o];
    } else v = root[(size_t)(k - R * C1) * C2 + o];
    Bt[(size_t)o * 1152 + k] = f2bs(v);
}
__global__ void k_b2(const float* __restrict__ comp, const float* __restrict__ basis,
                     const float* __restrict__ root, u16* __restrict__ Bt) {
    int t = blockIdx.x * blockDim.x + threadIdx.x;
    if (t >= C3 * 2304) return;
    int o = t % C3, k = t / C3;
    float v;
    if (k < R * C2) {
        int r = k >> 8, i = k & 255;
        v = 0.f;
        for (int b = 0; b < NB; ++b)
            v += comp[r * NB + b] * basis[((size_t)b * C2 + i) * C3 + o];
    } else v = root[(size_t)(k - R * C2) * C3 + o];
    Bt[(size_t)o * 2304 + k] = f2bs(v);
}
__global__ void k_btf(const float* __restrict__ Wf, u16* __restrict__ Bt) {
    int t = blockIdx.x * blockDim.x + threadIdx.x;
    if (t >= C3 * C3) return;
    int o = t % C3, k = t / C3;
    Bt[(size_t)o * C3 + k] = f2bs(Wf[(size_t)k * C3 + o]);
}

// ---- x fp32 -> bf16 ----
__global__ void k_f2b(const float* __restrict__ s, u16* __restrict__ d, long long n) {
    long long t = (long long)blockIdx.x * blockDim.x + threadIdx.x;
    if (t < n) d[t] = f2bs(s[t]);
}

// ---- CSR build ----
__global__ void k_count(const int* __restrict__ tgt, const int* __restrict__ ety,
                        int* __restrict__ cnt) {
    int e = blockIdx.x * blockDim.x + threadIdx.x;
    if (e >= N_EDGES) return;
    atomicAdd(&cnt[tgt[e] * R + ety[e]], 1);
}
__global__ void k_scan1(const int* __restrict__ cnt, int* __restrict__ off,
                        int* __restrict__ bsum) {
    __shared__ int s[256];
    int tid = threadIdx.x;
    int i = blockIdx.x * 256 + tid;
    int v = (i < NR) ? cnt[i] : 0;
    s[tid] = v;
    __syncthreads();
    for (int o = 1; o < 256; o <<= 1) {
        int x = (tid >= o) ? s[tid - o] : 0;
        __syncthreads();
        s[tid] += x;
        __syncthreads();
    }
    if (i < NR) off[i] = s[tid] - v;            // exclusive within block
    if (tid == 255) bsum[blockIdx.x] = s[255];
}
__global__ void k_scan2(int* __restrict__ bsum, int nb) {
    __shared__ int s[256];
    __shared__ int carry_s;
    int tid = threadIdx.x;
    if (tid == 0) carry_s = 0;
    __syncthreads();
    for (int base = 0; base < nb; base += 256) {
        int i = base + tid;
        int v = (i < nb) ? bsum[i] : 0;
        s[tid] = v;
        __syncthreads();
        for (int o = 1; o < 256; o <<= 1) {
            int x = (tid >= o) ? s[tid - o] : 0;
            __syncthreads();
            s[tid] += x;
            __syncthreads();
        }
        int carry = carry_s;
        if (i < nb) bsum[i] = s[tid] - v + carry;
        int tot = s[255];
        __syncthreads();
        if (tid == 0) carry_s = carry + tot;
        __syncthreads();
    }
}
__global__ void k_scan3(int* __restrict__ off, const int* __restrict__ bsum,
                        int* __restrict__ cursor) {
    int i = blockIdx.x * 256 + threadIdx.x;
    if (i < NR) {
        int v = off[i] + bsum[blockIdx.x];
        off[i] = v;
        cursor[i] = v;
    }
    if (i == 0) off[NR] = N_EDGES;
}
__global__ void k_fill(const int* __restrict__ src, const int* __restrict__ tgt,
                       const int* __restrict__ ety, int* __restrict__ cursor,
                       int* __restrict__ esrc) {
    int e = blockIdx.x * blockDim.x + threadIdx.x;
    if (e >= N_EDGES) return;
    int pos = atomicAdd(&cursor[tgt[e] * R + ety[e]], 1);
    esrc[pos] = src[e];
}

// ---- MFMA bf16 GEMM, 256x256 8-phase schedule, optional FUSED GATHER A ----
// C[M,CN] (+)= A @ Bt^T (+ bias), optional fused col-stats.
// BM=BN=256, BK=64; 8 waves (2M x 4N), wave tile 128x64; 128 KB dynamic LDS.
// GATHER mode: A-cols < Ksplit are per-(node,rel) MEANS computed inline from
// gsrc via CSR (off/esrc) during the A-staging phases — the gather work runs
// in the post-MFMA slack; the ds_write uses the SAME swizzled layout formula
// the gl_lds16 path wrote (content chunk (pos^l8) at position pos), so A is
// bitwise identical to the materialized-regionA path. A-cols >= Ksplit come
// from A1 via gl_lds16 (R6-proven). ds_writes are fenced with lgkmcnt(0)
// before the phase-closing barrier; consumers are >=4 barriers later.
// vmcnt discipline: non-GATHER keeps the proven single vmcnt(2) at P3-close;
// GATHER uses vmcnt(0) there (per-lane gather loads make counted vmcnt
// nondeterministic — R7 lesson class; B is L2-hot so the drain is cheap).
// Chunk-XOR LDS swizzle (both-sides, rule #21) + bijective XCD swizzle (m204).
template<int CN, typename OT, bool ACC, bool BIAS, bool STATS, bool GATHER, int CIN_LOG>
__global__ __launch_bounds__(512, 2) void k_mgemm(
        const u16* __restrict__ A0, int sA0, int Ksplit,
        const u16* __restrict__ A1, int sA1, int Ktot,
        const u16* __restrict__ Bt, int sB,
        const float* __restrict__ bias, OT* __restrict__ C, int M,
        float* __restrict__ sumv, float* __restrict__ ssv,
        const int* __restrict__ off, const int* __restrict__ esrc,
        const u16* __restrict__ gsrc, int R0) {
    extern __shared__ u16 lds[];
    u16* const Asl = lds;                 // 2 slots x 16384 elems (256 rows x 64)
    u16* const Bsl = lds + 32768;         // 2 slots x 16384

    const int tid = threadIdx.x;
    const int lane = tid & 63, w = tid >> 6;
    const int wm = w >> 2, wn = w & 3;            // 2M x 4N wave grid
    const int ml = lane & 15, qq = lane >> 4;
    const int ml7 = ml & 7;
    const int p0 = qq ^ ml7;
    const int p1 = (4 + qq) ^ ml7;
    const int aoff0 = (wm * 128 + ml) * 64 + p0 * 8;
    const int aoff1 = (wm * 128 + ml) * 64 + p1 * 8;
    const int boff0 = (wn * 64 + ml) * 64 + p0 * 8;
    const int boff1 = (wn * 64 + ml) * 64 + p1 * 8;

    // bijective XCD-aware swizzle on the linear block id
    const int nbx = gridDim.x;
    const int nwg = nbx * (int)gridDim.y;
    const int orig = blockIdx.y * nbx + blockIdx.x;
    const int qc = nwg >> 3, rc = nwg & 7;
    const int xcd = orig & 7, lin = orig >> 3;
    const int wgid = (xcd < rc ? xcd * (qc + 1) : rc * (qc + 1) + (xcd - rc) * qc) + lin;
    const int col0 = (wgid % nbx) * 256;
    const int row0 = (wgid / nbx) * 256;

    // staging geometry: wave covers rows 16w..16w+16 of each 128-row half;
    // lane handles row (c-strip, l8) and content chunk csrc (pre-swizzled)
    const int l8 = lane >> 3;
    const int csrc = ((lane & 7) ^ l8) * 8;
    const u16* A1g = A1 ? A1 : A0;
    const int  sA1g = A1 ? sA1 : sA0;
    int gnode[2][2];
    const u16* bA0[2][2];
    const u16* bA1[2][2];
    const u16* bB[2][2];
    #pragma unroll
    for (int h = 0; h < 2; ++h)
        #pragma unroll
        for (int c = 0; c < 2; ++c) {
            int rj = (2 * w + c) * 8 + l8;
            int ga = row0 + h * 128 + rj; if (ga >= M) ga = M - 1;
            gnode[h][c] = ga;
            bA0[h][c] = A0 + (size_t)ga * sA0 + csrc;
            bA1[h][c] = A1g + (size_t)ga * sA1g + csrc;
            bB[h][c]  = Bt + (size_t)(col0 + h * 128 + rj) * sB + csrc;
        }

    const int NT = Ktot >> 6;
    const int ks64 = Ksplit >> 6;

    auto glA = [&](int ts, int h, u16* slot) {
        const u16* a0 = (ts < ks64) ? bA0[h][0] + (size_t)ts * 64
                                    : bA1[h][0] + (size_t)(ts - ks64) * 64;
        const u16* a1 = (ts < ks64) ? bA0[h][1] + (size_t)ts * 64
                                    : bA1[h][1] + (size_t)(ts - ks64) * 64;
        gl_lds16(a0, slot + h * 8192 + (2 * w + 0) * 512);
        gl_lds16(a1, slot + h * 8192 + (2 * w + 1) * 512);
    };
    auto glB = [&](int ts, int h, u16* slot) {
        gl_lds16(bB[h][0] + (size_t)ts * 64, slot + h * 8192 + (2 * w + 0) * 512);
        gl_lds16(bB[h][1] + (size_t)ts * 64, slot + h * 8192 + (2 * w + 1) * 512);
    };
    // fused gather A-staging: mean over CSR segment, same LDS layout as glA
    auto gstage = [&](int ts, int h, u16* slot) {
        if constexpr (GATHER) {
            const int rel = R0 + (ts >> (CIN_LOG - 6));
            const int cb = (ts & ((1 << (CIN_LOG - 6)) - 1)) * 64 + csrc;
            #pragma unroll
            for (int c = 0; c < 2; ++c) {
                const int seg = gnode[h][c] * R + rel;
                const int o0 = off[seg], o1 = off[seg + 1];
                float a[8] = {};
                for (int j = o0; j < o1; ++j) {
                    int s = esrc[j];
                    short8 v = *(const short8*)(gsrc + ((size_t)s << CIN_LOG) + cb);
                    #pragma unroll
                    for (int k2 = 0; k2 < 8; ++k2) a[k2] += b2f((u16)v[k2]);
                }
                float wt = (o1 > o0) ? 1.f / (float)(o1 - o0) : 0.f;
                short8 ov;
                #pragma unroll
                for (int k2 = 0; k2 < 8; ++k2) ov[k2] = (short)f2bs(a[k2] * wt);
                *(short8*)(slot + h * 8192 + (2 * w + c) * 512 + lane * 8) = ov;
            }
        }
    };

    // prologue: B(0) both halves first, then A(0) h0,h1 and A(1) h0.
    // Gather consumes its loads (issued after B) -> in-order drain covers B.
    glB(0, 0, Bsl); glB(0, 1, Bsl);
    {
        u16* s0 = Asl; u16* s1 = Asl + 16384;
        if (GATHER && 0 < ks64) gstage(0, 0, s0); else glA(0, 0, s0);
        if (GATHER && 0 < ks64) gstage(0, 1, s0); else glA(0, 1, s0);
        if (GATHER && 1 < ks64) gstage(1, 0, s1); else glA(1, 0, s1);
    }
    if constexpr (GATHER) {
        asm volatile("s_waitcnt lgkmcnt(0)" ::: "memory");
        asm volatile("s_waitcnt vmcnt(0)" ::: "memory");
    } else {
        asm volatile("s_waitcnt vmcnt(2)" ::: "memory");
    }
    __builtin_amdgcn_s_barrier();

    floatx4 acc[8][4] = {};
    short8 af[4][2], bfr[2][2];

    for (int t = 0; t < NT; ++t) {
        const int s = t & 1;
        u16* const As_s = Asl + s * 16384;
        u16* const Bs_s = Bsl + s * 16384;
        u16* const As_u = Asl + (s ^ 1) * 16384;
        u16* const Bs_u = Bsl + (s ^ 1) * 16384;
        const bool st1 = (t + 1 < NT), st2 = (t + 2 < NT);
        const bool g1 = GATHER && (t + 1) < ks64;   // stage A-h1(t+1) via gather?
        const bool g2 = GATHER && (t + 2) < ks64;   // stage A-h0(t+2) via gather?

        // ---- P0: read A m0-3 + B n0-1 ; stage A-h1(t+1) -> slot u
        #pragma unroll
        for (int m = 0; m < 4; ++m) {
            af[m][0] = *(const short8*)(As_s + aoff0 + m * 1024);
            af[m][1] = *(const short8*)(As_s + aoff1 + m * 1024);
        }
        #pragma unroll
        for (int n = 0; n < 2; ++n) {
            bfr[n][0] = *(const short8*)(Bs_s + boff0 + n * 1024);
            bfr[n][1] = *(const short8*)(Bs_s + boff1 + n * 1024);
        }
        if (st1 && !g1) glA(t + 1, 1, As_u);
        __builtin_amdgcn_s_barrier();
        asm volatile("s_waitcnt lgkmcnt(0)" ::: "memory");
        __builtin_amdgcn_sched_barrier(0);
        __builtin_amdgcn_s_setprio(1);
        #pragma unroll
        for (int m = 0; m < 4; ++m)
            #pragma unroll
            for (int n = 0; n < 2; ++n) {
                acc[m][n] = __builtin_amdgcn_mfma_f32_16x16x32_bf16(af[m][0], bfr[n][0], acc[m][n], 0, 0, 0);
                acc[m][n] = __builtin_amdgcn_mfma_f32_16x16x32_bf16(af[m][1], bfr[n][1], acc[m][n], 0, 0, 0);
            }
        __builtin_amdgcn_s_setprio(0);
        if constexpr (GATHER) {
            if (st1 && g1) gstage(t + 1, 1, As_u);
            asm volatile("s_waitcnt lgkmcnt(0)" ::: "memory");
        }
        __builtin_amdgcn_s_barrier();

        // ---- P1: read B n2-3 ; stage B-h0(t+1)
        #pragma unroll
        for (int n = 0; n < 2; ++n) {
            bfr[n][0] = *(const short8*)(Bs_s + boff0 + (2 + n) * 1024);
            bfr[n][1] = *(const short8*)(Bs_s + boff1 + (2 + n) * 1024);
        }
        if (st1) glB(t + 1, 0, Bs_u);
        __builtin_amdgcn_s_barrier();
        asm volatile("s_waitcnt lgkmcnt(0)" ::: "memory");
        __builtin_amdgcn_sched_barrier(0);
        __builtin_amdgcn_s_setprio(1);
        #pragma unroll
        for (int m = 0; m < 4; ++m)
            #pragma unroll
            for (int n = 0; n < 2; ++n) {
                acc[m][n + 2] = __builtin_amdgcn_mfma_f32_16x16x32_bf16(af[m][0], bfr[n][0], acc[m][n + 2], 0, 0, 0);
                acc[m][n + 2] = __builtin_amdgcn_mfma_f32_16x16x32_bf16(af[m][1], bfr[n][1], acc[m][n + 2], 0, 0, 0);
            }
        __builtin_amdgcn_s_setprio(0);
        __builtin_amdgcn_s_barrier();

        // ---- P2: read A m4-7 ; stage B-h1(t+1)
        #pragma unroll
        for (int m = 0; m < 4; ++m) {
            af[m][0] = *(const short8*)(As_s + aoff0 + (4 + m) * 1024);
            af[m][1] = *(const short8*)(As_s + aoff1 + (4 + m) * 1024);
        }
        if (st1) glB(t + 1, 1, Bs_u);
        __builtin_amdgcn_s_barrier();
        asm volatile("s_waitcnt lgkmcnt(0)" ::: "memory");
        __builtin_amdgcn_sched_barrier(0);
        __builtin_amdgcn_s_setprio(1);
        #pragma unroll
        for (int m = 0; m < 4; ++m)
            #pragma unroll
            for (int n = 0; n < 2; ++n) {
                acc[4 + m][n + 2] = __builtin_amdgcn_mfma_f32_16x16x32_bf16(af[m][0], bfr[n][0], acc[4 + m][n + 2], 0, 0, 0);
                acc[4 + m][n + 2] = __builtin_amdgcn_mfma_f32_16x16x32_bf16(af[m][1], bfr[n][1], acc[4 + m][n + 2], 0, 0, 0);
            }
        __builtin_amdgcn_s_setprio(0);
        __builtin_amdgcn_s_barrier();

        // ---- P3: read B n0-1 ; stage A-h0(t+2) -> slot s ; tile close
        #pragma unroll
        for (int n = 0; n < 2; ++n) {
            bfr[n][0] = *(const short8*)(Bs_s + boff0 + n * 1024);
            bfr[n][1] = *(const short8*)(Bs_s + boff1 + n * 1024);
        }
        if (st2 && !g2) glA(t + 2, 0, As_s);
        __builtin_amdgcn_s_barrier();
        asm volatile("s_waitcnt lgkmcnt(0)" ::: "memory");
        __builtin_amdgcn_sched_barrier(0);
        __builtin_amdgcn_s_setprio(1);
        #pragma unroll
        for (int m = 0; m < 4; ++m)
            #pragma unroll
            for (int n = 0; n < 2; ++n) {
                acc[4 + m][n] = __builtin_amdgcn_mfma_f32_16x16x32_bf16(af[m][0], bfr[n][0], acc[4 + m][n], 0, 0, 0);
                acc[4 + m][n] = __builtin_amdgcn_mfma_f32_16x16x32_bf16(af[m][1], bfr[n][1], acc[4 + m][n], 0, 0, 0);
            }
        __builtin_amdgcn_s_setprio(0);
        if constexpr (GATHER) {
            if (st2 && g2) gstage(t + 2, 0, As_s);
            asm volatile("s_waitcnt lgkmcnt(0)" ::: "memory");
            asm volatile("s_waitcnt vmcnt(0)" ::: "memory");
        } else {
            asm volatile("s_waitcnt vmcnt(2)" ::: "memory");
        }
        __builtin_amdgcn_s_barrier();
    }

    // ---- epilogue: C write (rows guarded) + optional fused col-stats ----
    float cs[4] = {}, cq[4] = {};
    #pragma unroll
    for (int m = 0; m < 8; ++m) {
        #pragma unroll
        for (int rr = 0; rr < 4; ++rr) {
            int grow = row0 + wm * 128 + m * 16 + qq * 4 + rr;
            if (grow >= M) continue;
            #pragma unroll
            for (int n = 0; n < 4; ++n) {
                int gcol = col0 + wn * 64 + n * 16 + ml;
                float v = acc[m][n][rr];
                if (BIAS) v += bias[gcol];
                size_t idx = (size_t)grow * CN + gcol;
                if (ACC) v += ldacc(&C[idx]);
                if (STATS) { cs[n] += v; cq[n] += v * v; }
                stv(&C[idx], v);
            }
        }
    }
    if (STATS) {
        #pragma unroll
        for (int n = 0; n < 4; ++n) {
            float s2 = cs[n];
            s2 += __shfl_xor(s2, 16); s2 += __shfl_xor(s2, 32);
            float q2 = cq[n];
            q2 += __shfl_xor(q2, 16); q2 += __shfl_xor(q2, 32);
            if (lane < 16) {
                int gcol = col0 + wn * 64 + n * 16 + ml;
                atomicAdd(&sumv[gcol], s2);
                atomicAdd(&ssv[gcol], q2);
            }
        }
    }
}

// ---- BN prep: per-column scale/shift from fused stats ----
__global__ void k_bnprep(const float* __restrict__ sum, const float* __restrict__ ss,
                         const float* __restrict__ gamma, const float* __restrict__ beta,
                         float* __restrict__ scale, float* __restrict__ shift, int C) {
    int c = blockIdx.x * blockDim.x + threadIdx.x;
    if (c >= C) return;
    const float invN = 1.0f / (float)N_NODES;
    float mu = sum[c] * invN;
    float var = ss[c] * invN - mu * mu;
    float sc = rsqrtf(fmaxf(var, 0.f) + BN_EPS) * gamma[c];
    scale[c] = sc;
    shift[c] = beta[c] - mu * sc;
}

// ---- BatchNorm + LeakyReLU, bf16 in place, short8 vectorized ----
template<int C>
__global__ void k_bn8(u16* __restrict__ h, const float* __restrict__ scale,
                      const float* __restrict__ shift) {
    long long t = (long long)blockIdx.x * blockDim.x + threadIdx.x;
    if (t >= (long long)N_NODES * C / 8) return;
    long long base = t << 3;
    int c0 = (int)(base & (C - 1));
    short8 v = *(const short8*)&h[base];
    short8 o;
    #pragma unroll
    for (int k = 0; k < 8; ++k) {
        float y = b2f((u16)v[k]) * scale[c0 + k] + shift[c0 + k];
        o[k] = (short)f2bs(y > 0.f ? y : ALPHA * y);
    }
    *(short8*)&h[base] = o;
}

extern "C" void kernel_launch(void* const* d_in, const int* in_sizes, int n_in,
                              void* d_out, int out_size, void* d_ws, size_t ws_size,
                              hipStream_t stream) {
    const float* x      = (const float*)d_in[0];
    const int*   ei     = (const int*)d_in[1];
    const int*   ety    = (const int*)d_in[2];
    const float* basis1 = (const float*)d_in[3];
    const float* comp1  = (const float*)d_in[4];
    const float* root1  = (const float*)d_in[5];
    const float* bias1  = (const float*)d_in[6];
    const float* gamma1 = (const float*)d_in[7];
    const float* beta1  = (const float*)d_in[8];
    const float* basis2 = (const float*)d_in[9];
    const float* comp2  = (const float*)d_in[10];
    const float* root2  = (const float*)d_in[11];
    const float* bias2  = (const float*)d_in[12];
    const float* gamma2 = (const float*)d_in[13];
    const float* beta2  = (const float*)d_in[14];
    const float* Wf     = (const float*)d_in[15];
    const float* bf_    = (const float*)d_in[16];
    const int* src = ei;
    const int* tgt = ei + N_EDGES;

    // opt-in to 128 KB dynamic LDS for the GEMM instantiations (idempotent)
    static bool attr_done = false;
    if (!attr_done) {
        hipFuncSetAttribute((const void*)k_mgemm<C2, u16, false, true, true, true, 7>,
                            hipFuncAttributeMaxDynamicSharedMemorySize, 131072);
        hipFuncSetAttribute((const void*)k_mgemm<C3, u16, false, true, false, true, 8>,
                            hipFuncAttributeMaxDynamicSharedMemorySize, 131072);
        hipFuncSetAttribute((const void*)k_mgemm<C3, u16, true, false, true, true, 8>,
                            hipFuncAttributeMaxDynamicSharedMemorySize, 131072);
        hipFuncSetAttribute((const void*)k_mgemm<C3, float, false, true, false, false, 8>,
                            hipFuncAttributeMaxDynamicSharedMemorySize, 131072);
        attr_done = true;
    }

    // ---- workspace layout (~105 MB; regionA eliminated) ----
    const int nscanb = (NR + 255) / 256;    // 1563
    char* p = (char*)d_ws;
    auto alloc = [&](size_t bytes) { void* r = (void*)p; p += (bytes + 63) & ~63ULL; return r; };
    u16* h1bf    = (u16*)alloc((size_t)N_NODES * C2 * 2);       // 25.6 MB
    u16* h2bf    = (u16*)alloc((size_t)N_NODES * C3 * 2);       // 51.2 MB
    u16* xbf     = (u16*)alloc((size_t)N_NODES * C1 * 2);       // 12.8 MB
    int* cnt     = (int*)alloc((size_t)NR * 4);
    int* off     = (int*)alloc((size_t)(NR + 1) * 4);
    int* cursor  = (int*)alloc((size_t)NR * 4);
    int* esrc    = (int*)alloc((size_t)N_EDGES * 4);
    int* bsum    = (int*)alloc((size_t)nscanb * 4);
    u16* Bt1     = (u16*)alloc((size_t)C2 * 1152 * 2);
    u16* Bt2     = (u16*)alloc((size_t)C3 * 2304 * 2);
    u16* Btf     = (u16*)alloc((size_t)C3 * C3 * 2);
    float* stats = (float*)alloc(3072 * 4);
    float* sum1 = stats, *ss1 = stats + 256, *sum2 = stats + 512, *ss2 = stats + 1024;
    float* sc1 = stats + 1536, *sh1 = stats + 1792;
    float* sc2 = stats + 2048, *sh2 = stats + 2560;

    hipMemsetAsync(cnt, 0, (size_t)NR * 4, stream);
    hipMemsetAsync(stats, 0, 1536 * 4, stream);

    // weights + x->bf16 + CSR
    k_b1<<<cdivu((long long)C2 * 1152, 256), 256, 0, stream>>>(comp1, basis1, root1, Bt1);
    k_b2<<<cdivu((long long)C3 * 2304, 256), 256, 0, stream>>>(comp2, basis2, root2, Bt2);
    k_btf<<<cdivu((long long)C3 * C3, 256), 256, 0, stream>>>(Wf, Btf);
    k_f2b<<<cdivu((long long)N_NODES * C1, 256), 256, 0, stream>>>(x, xbf, (long long)N_NODES * C1);
    k_count<<<cdivu(N_EDGES, 256), 256, 0, stream>>>(tgt, ety, cnt);
    k_scan1<<<nscanb, 256, 0, stream>>>(cnt, off, bsum);
    k_scan2<<<1, 256, 0, stream>>>(bsum, nscanb);
    k_scan3<<<nscanb, 256, 0, stream>>>(off, bsum, cursor);
    k_fill<<<cdivu(N_EDGES, 256), 256, 0, stream>>>(src, tgt, ety, cursor, esrc);

    const unsigned gym = cdivu(N_NODES, 256);   // 196

    // ---- layer 1: A = [gathered means x8 rels | x], K=1152 -> h1bf (stats fused)
    {
        dim3 g(C2 / 256, gym);
        k_mgemm<C2, u16, false, true, true, true, 7><<<g, 512, 131072, stream>>>(
            xbf, C1, 1024, xbf, C1, 1152, Bt1, 1152, bias1, h1bf, N_NODES, sum1, ss1,
            off, esrc, xbf, 0);
    }
    k_bnprep<<<1, C2, 0, stream>>>(sum1, ss1, gamma1, beta1, sc1, sh1, C2);
    k_bn8<C2><<<cdivu((long long)N_NODES * C2 / 8, 256), 256, 0, stream>>>(h1bf, sc1, sh1);

    // ---- layer 2: h2 = [means r0..3]@W + bias, += [means r4..7 | h1]@W (gathers fused)
    {
        dim3 g(C3 / 256, gym);
        k_mgemm<C3, u16, false, true, false, true, 8><<<g, 512, 131072, stream>>>(
            h1bf, C2, 1024, h1bf, C2, 1024, Bt2, 2304, bias2, h2bf, N_NODES,
            nullptr, nullptr, off, esrc, h1bf, 0);
        k_mgemm<C3, u16, true, false, true, true, 8><<<g, 512, 131072, stream>>>(
            h1bf, C2, 1024, h1bf, C2, 1280, Bt2 + 1024, 2304, nullptr, h2bf, N_NODES,
            sum2, ss2, off, esrc, h1bf, 4);
    }
    k_bnprep<<<1, C3, 0, stream>>>(sum2, ss2, gamma2, beta2, sc2, sh2, C3);
    k_bn8<C3><<<cdivu((long long)N_NODES * C3 / 8, 256), 256, 0, stream>>>(h2bf, sc2, sh2);

    // ---- final linear -> fp32 out ----
    {
        dim3 g(C3 / 256, gym);
        k_mgemm<C3, float, false, true, false, false, 8><<<g, 512, 131072, stream>>>(
            h2bf, C3, 512, (const u16*)nullptr, 0, 512, Btf, C3, bf_, (float*)d_out, N_NODES,
            nullptr, nullptr, nullptr, nullptr, nullptr, 0);
    }
}

// Round 10
// 788.265 us; speedup vs baseline: 1.9755x; 1.9755x over previous
//
#include <hip/hip_runtime.h>
#include <hip/hip_bf16.h>

#define N_NODES 50000
#define N_EDGES 800000
#define R 8
#define NB 30
#define C1 128
#define C2 256
#define C3 512
#define NR (N_NODES * R)
#define BN_EPS 1e-5f
#define ALPHA 0.01f
#define XSTRIDE 1024          // regionA row stride (bf16 elems), both layers

typedef unsigned short u16;
typedef __attribute__((ext_vector_type(8))) short short8;
typedef __attribute__((ext_vector_type(4))) float floatx4;

static inline unsigned cdivu(long long a, long long b) { return (unsigned)((a + b - 1) / b); }

__device__ __forceinline__ u16 f2bs(float f) {
    __hip_bfloat16 h = __float2bfloat16(f);
    return *reinterpret_cast<u16*>(&h);
}
__device__ __forceinline__ float b2f(u16 u) {
    return __uint_as_float(((unsigned)u) << 16);
}
__device__ __forceinline__ float ldacc(const float* p) { return *p; }
__device__ __forceinline__ float ldacc(const u16* p) { return b2f(*p); }
__device__ __forceinline__ void stv(float* p, float v) { *p = v; }
__device__ __forceinline__ void stv(u16* p, float v) { *p = f2bs(v); }

// async global->LDS, 16B per lane; LDS dest is wave-uniform base + lane*16
__device__ __forceinline__ void gl_lds16(const u16* g, u16* l) {
    __builtin_amdgcn_global_load_lds(
        (const __attribute__((address_space(1))) void*)g,
        (__attribute__((address_space(3))) void*)l, 16, 0, 0);
}

// ---- weight builders: Bt[o][k] bf16, k = [rel-blocks | root] ----
__global__ void k_b1(const float* __restrict__ comp, const float* __restrict__ basis,
                     const float* __restrict__ root, u16* __restrict__ Bt) {
    int t = blockIdx.x * blockDim.x + threadIdx.x;
    if (t >= C2 * 1152) return;
    int o = t % C2, k = t / C2;         // coalesced basis/root reads over o
    float v;
    if (k < R * C1) {
        int r = k >> 7, i = k & 127;
        v = 0.f;
        for (int b = 0; b < NB; ++b)
            v += comp[r * NB + b] * basis[((size_t)b * C1 + i) * C2 + o];
    } else v = root[(size_t)(k - R * C1) * C2 + o];
    Bt[(size_t)o * 1152 + k] = f2bs(v);
}
__global__ void k_b2(const float* __restrict__ comp, const float* __restrict__ basis,
                     const float* __restrict__ root, u16* __restrict__ Bt) {
    int t = blockIdx.x * blockDim.x + threadIdx.x;
    if (t >= C3 * 2304) return;
    int o = t % C3, k = t / C3;
    float v;
    if (k < R * C2) {
        int r = k >> 8, i = k & 255;
        v = 0.f;
        for (int b = 0; b < NB; ++b)
            v += comp[r * NB + b] * basis[((size_t)b * C2 + i) * C3 + o];
    } else v = root[(size_t)(k - R * C2) * C3 + o];
    Bt[(size_t)o * 2304 + k] = f2bs(v);
}
__global__ void k_btf(const float* __restrict__ Wf, u16* __restrict__ Bt) {
    int t = blockIdx.x * blockDim.x + threadIdx.x;
    if (t >= C3 * C3) return;
    int o = t % C3, k = t / C3;
    Bt[(size_t)o * C3 + k] = f2bs(Wf[(size_t)k * C3 + o]);
}

// ---- x fp32 -> bf16 ----
__global__ void k_f2b(const float* __restrict__ s, u16* __restrict__ d, long long n) {
    long long t = (long long)blockIdx.x * blockDim.x + threadIdx.x;
    if (t < n) d[t] = f2bs(s[t]);
}

// ---- CSR build ----
__global__ void k_count(const int* __restrict__ tgt, const int* __restrict__ ety,
                        int* __restrict__ cnt) {
    int e = blockIdx.x * blockDim.x + threadIdx.x;
    if (e >= N_EDGES) return;
    atomicAdd(&cnt[tgt[e] * R + ety[e]], 1);
}
__global__ void k_scan1(const int* __restrict__ cnt, int* __restrict__ off,
                        int* __restrict__ bsum) {
    __shared__ int s[256];
    int tid = threadIdx.x;
    int i = blockIdx.x * 256 + tid;
    int v = (i < NR) ? cnt[i] : 0;
    s[tid] = v;
    __syncthreads();
    for (int o = 1; o < 256; o <<= 1) {
        int x = (tid >= o) ? s[tid - o] : 0;
        __syncthreads();
        s[tid] += x;
        __syncthreads();
    }
    if (i < NR) off[i] = s[tid] - v;            // exclusive within block
    if (tid == 255) bsum[blockIdx.x] = s[255];
}
__global__ void k_scan2(int* __restrict__ bsum, int nb) {
    __shared__ int s[256];
    __shared__ int carry_s;
    int tid = threadIdx.x;
    if (tid == 0) carry_s = 0;
    __syncthreads();
    for (int base = 0; base < nb; base += 256) {
        int i = base + tid;
        int v = (i < nb) ? bsum[i] : 0;
        s[tid] = v;
        __syncthreads();
        for (int o = 1; o < 256; o <<= 1) {
            int x = (tid >= o) ? s[tid - o] : 0;
            __syncthreads();
            s[tid] += x;
            __syncthreads();
        }
        int carry = carry_s;
        if (i < nb) bsum[i] = s[tid] - v + carry;
        int tot = s[255];
        __syncthreads();
        if (tid == 0) carry_s = carry + tot;
        __syncthreads();
    }
}
__global__ void k_scan3(int* __restrict__ off, const int* __restrict__ bsum,
                        int* __restrict__ cursor) {
    int i = blockIdx.x * 256 + threadIdx.x;
    if (i < NR) {
        int v = off[i] + bsum[blockIdx.x];
        off[i] = v;
        cursor[i] = v;
    }
    if (i == 0) off[NR] = N_EDGES;
}
__global__ void k_fill(const int* __restrict__ src, const int* __restrict__ tgt,
                       const int* __restrict__ ety, int* __restrict__ cursor,
                       int* __restrict__ esrc) {
    int e = blockIdx.x * blockDim.x + threadIdx.x;
    if (e >= N_EDGES) return;
    int pos = atomicAdd(&cursor[tgt[e] * R + ety[e]], 1);
    esrc[pos] = src[e];
}

// ---- gather: mean of src rows per (tgt, rel), bf16 in/out, no atomics ----
// Subwave-per-edge: wave per (t, rr) segment; LPR = CIN/8 lanes load one full
// row as short8 (16B/lane), NSW = 64/LPR subwaves each handle a different
// edge concurrently. Cross-subwave combine: shfl_xor tree; subwave 0 writes.
// NOTE (R9 lesson): do NOT fuse this into the GEMM — per-lane scattered 16B
// reads + CSR chains inside the barrier-locked phases collapsed BW to 400GB/s.
template<int CIN, int NREL>
__global__ void k_gather(const int* __restrict__ off, const int* __restrict__ esrc,
                         const u16* __restrict__ srcbf, u16* __restrict__ Xbar, int r0) {
    constexpr int LPR = CIN / 8;        // lanes per row: 16 (C1) or 32 (C2)
    constexpr int NSW = 64 / LPR;       // subwaves: 4 or 2
    int wid = blockIdx.x * 4 + (threadIdx.x >> 6);
    if (wid >= N_NODES * NREL) return;
    int lane = threadIdx.x & 63;
    int sw = lane / LPR, l = lane & (LPR - 1);
    int t = wid / NREL, rr = wid - t * NREL;
    int b = t * R + r0 + rr;
    int o0 = off[b], o1 = off[b + 1];
    float acc[8] = {};
    for (int j = o0; j < o1; j += NSW) {
        int e = j + sw;
        if (e < o1) {
            int s = esrc[e];
            short8 v = *(const short8*)&srcbf[(size_t)s * CIN + l * 8];
            #pragma unroll
            for (int k = 0; k < 8; ++k) acc[k] += b2f((u16)v[k]);
        }
    }
    #pragma unroll
    for (int m = LPR; m < 64; m <<= 1)
        #pragma unroll
        for (int k = 0; k < 8; ++k) acc[k] += __shfl_xor(acc[k], m);
    int deg = o1 - o0;
    float w = (deg > 0) ? 1.f / (float)deg : 0.f;
    if (sw == 0) {
        short8 ov;
        #pragma unroll
        for (int k = 0; k < 8; ++k) ov[k] = (short)f2bs(acc[k] * w);
        *(short8*)&Xbar[(size_t)t * XSTRIDE + rr * CIN + l * 8] = ov;
    }
}

// ---- MFMA bf16 GEMM, 256x256 8-phase schedule (R6-proven sync discipline) ----
// C[M,CN] (+)= [A0|A1](bf16) @ Bt^T (+ bias), optional fused col-stats.
// BM=BN=256, BK=64; 8 waves (2M x 4N), wave tile 128x64; 128 KB dynamic LDS.
// Per K-tile: 4 phases {ds_reads ; 1 half-tile gl_lds prefetch ; s_barrier ;
// lgkmcnt(0)+sched_barrier(0) ; setprio(1) ; 16 MFMA ; setprio(0) ; s_barrier}.
// SINGLE counted s_waitcnt vmcnt(2) at P3-close (proven R5/R6/R8): at tile-t+1
// start only t's P3 loads (A-h0 t+2) are in flight, so B-h1(t+1) [staged t.P2]
// is guaranteed landed before wn>=2 waves read it at t+1.P0. Do NOT relax —
// vmcnt(4) races (R7 failure).
// Chunk-XOR LDS swizzle (both-sides, rule #21) + bijective XCD swizzle (m204).
// STATS: epilogue accumulates per-column sum/ssq of final v (fused colstats).
template<int CN, typename OT, bool ACC, bool BIAS, bool STATS>
__global__ __launch_bounds__(512, 2) void k_mgemm(
        const u16* __restrict__ A0, int sA0, int Ksplit,
        const u16* __restrict__ A1, int sA1, int Ktot,
        const u16* __restrict__ Bt, int sB,
        const float* __restrict__ bias, OT* __restrict__ C, int M,
        float* __restrict__ sumv, float* __restrict__ ssv) {
    extern __shared__ u16 lds[];
    u16* const Asl = lds;                 // 2 slots x 16384 elems (rows x 64)
    u16* const Bsl = lds + 32768;         // 2 slots x 16384

    const int tid = threadIdx.x;
    const int lane = tid & 63, w = tid >> 6;
    const int wm = w >> 2, wn = w & 3;            // 2M x 4N wave grid
    const int ml = lane & 15, qq = lane >> 4;
    const int ml7 = ml & 7;
    const int p0 = qq ^ ml7;
    const int p1 = (4 + qq) ^ ml7;
    const int aoff0 = (wm * 128 + ml) * 64 + p0 * 8;
    const int aoff1 = (wm * 128 + ml) * 64 + p1 * 8;
    const int boff0 = (wn * 64 + ml) * 64 + p0 * 8;
    const int boff1 = (wn * 64 + ml) * 64 + p1 * 8;

    // bijective XCD-aware swizzle on the linear block id
    const int nbx = gridDim.x;
    const int nwg = nbx * (int)gridDim.y;
    const int orig = blockIdx.y * nbx + blockIdx.x;
    const int qc = nwg >> 3, rc = nwg & 7;
    const int xcd = orig & 7, lin = orig >> 3;
    const int wgid = (xcd < rc ? xcd * (qc + 1) : rc * (qc + 1) + (xcd - rc) * qc) + lin;
    const int col0 = (wgid % nbx) * 256;
    const int row0 = (wgid / nbx) * 256;

    // staging geometry: each wave covers rows (2w+j)*8 .. +7 of a 128-row half
    const int l8 = lane >> 3;
    const int csrc = ((lane & 7) ^ l8) * 8;       // pre-swizzled source chunk
    const int rj0 = (2 * w + 0) * 8 + l8;
    const int rj1 = (2 * w + 1) * 8 + l8;
    const u16* A1g = A1 ? A1 : A0;
    const int  sA1g = A1 ? sA1 : sA0;
    int ga00 = row0 + rj0;        if (ga00 >= M) ga00 = M - 1;
    int ga01 = row0 + rj1;        if (ga01 >= M) ga01 = M - 1;
    int ga10 = row0 + 128 + rj0;  if (ga10 >= M) ga10 = M - 1;
    int ga11 = row0 + 128 + rj1;  if (ga11 >= M) ga11 = M - 1;
    const u16* pa00 = A0 + (size_t)ga00 * sA0 + csrc;   // A-h0 streams
    const u16* pa01 = A0 + (size_t)ga01 * sA0 + csrc;
    const u16* pa10 = A0 + (size_t)ga10 * sA0 + csrc;   // A-h1 streams
    const u16* pa11 = A0 + (size_t)ga11 * sA0 + csrc;
    const u16* ta00 = A1g + (size_t)ga00 * sA1g + csrc; // seg-1 bases
    const u16* ta01 = A1g + (size_t)ga01 * sA1g + csrc;
    const u16* ta10 = A1g + (size_t)ga10 * sA1g + csrc;
    const u16* ta11 = A1g + (size_t)ga11 * sA1g + csrc;
    const u16* pb00 = Bt + (size_t)(col0 + rj0) * sB + csrc;        // B-h0
    const u16* pb01 = Bt + (size_t)(col0 + rj1) * sB + csrc;
    const u16* pb10 = Bt + (size_t)(col0 + 128 + rj0) * sB + csrc;  // B-h1
    const u16* pb11 = Bt + (size_t)(col0 + 128 + rj1) * sB + csrc;

    const int dj0 = (2 * w + 0) * 512;    // LDS dest elem offset within half
    const int dj1 = (2 * w + 1) * 512;

    const int NT = Ktot >> 6;
    const int ks64 = Ksplit >> 6;

    // prologue: tile0 (A h0,h1; B h0,h1) -> slot0 ; A-h0 of tile1 -> slot1
    gl_lds16(pa00, Asl + dj0);          gl_lds16(pa01, Asl + dj1);          pa00 += 64; pa01 += 64;
    gl_lds16(pa10, Asl + 8192 + dj0);   gl_lds16(pa11, Asl + 8192 + dj1);   pa10 += 64; pa11 += 64;
    gl_lds16(pb00, Bsl + dj0);          gl_lds16(pb01, Bsl + dj1);          pb00 += 64; pb01 += 64;
    gl_lds16(pb10, Bsl + 8192 + dj0);   gl_lds16(pb11, Bsl + 8192 + dj1);   pb10 += 64; pb11 += 64;
    gl_lds16(pa00, Asl + 16384 + dj0);  gl_lds16(pa01, Asl + 16384 + dj1);  pa00 += 64; pa01 += 64;
    asm volatile("s_waitcnt vmcnt(2)" ::: "memory");
    __builtin_amdgcn_s_barrier();

    floatx4 acc[8][4] = {};
    short8 af[4][2], bfr[2][2];

    for (int t = 0; t < NT; ++t) {
        const int s = t & 1;
        u16* const As_s = Asl + s * 16384;
        u16* const Bs_s = Bsl + s * 16384;
        u16* const As_u = Asl + (s ^ 1) * 16384;
        u16* const Bs_u = Bsl + (s ^ 1) * 16384;
        if (t == ks64 - 1) { pa10 = ta10; pa11 = ta11; }
        if (t == ks64 - 2) { pa00 = ta00; pa01 = ta01; }
        const bool st1 = (t + 1 < NT), st2 = (t + 2 < NT);

        // ---- P0: read A m0-3 + B n0-1 ; stage A-h1(t+1) -> slot u
        #pragma unroll
        for (int m = 0; m < 4; ++m) {
            af[m][0] = *(const short8*)(As_s + aoff0 + m * 1024);
            af[m][1] = *(const short8*)(As_s + aoff1 + m * 1024);
        }
        #pragma unroll
        for (int n = 0; n < 2; ++n) {
            bfr[n][0] = *(const short8*)(Bs_s + boff0 + n * 1024);
            bfr[n][1] = *(const short8*)(Bs_s + boff1 + n * 1024);
        }
        if (st1) { gl_lds16(pa10, As_u + 8192 + dj0); gl_lds16(pa11, As_u + 8192 + dj1);
                   pa10 += 64; pa11 += 64; }
        __builtin_amdgcn_s_barrier();
        asm volatile("s_waitcnt lgkmcnt(0)" ::: "memory");
        __builtin_amdgcn_sched_barrier(0);
        __builtin_amdgcn_s_setprio(1);
        #pragma unroll
        for (int m = 0; m < 4; ++m)
            #pragma unroll
            for (int n = 0; n < 2; ++n) {
                acc[m][n] = __builtin_amdgcn_mfma_f32_16x16x32_bf16(af[m][0], bfr[n][0], acc[m][n], 0, 0, 0);
                acc[m][n] = __builtin_amdgcn_mfma_f32_16x16x32_bf16(af[m][1], bfr[n][1], acc[m][n], 0, 0, 0);
            }
        __builtin_amdgcn_s_setprio(0);
        __builtin_amdgcn_s_barrier();

        // ---- P1: read B n2-3 ; stage B-h0(t+1)
        #pragma unroll
        for (int n = 0; n < 2; ++n) {
            bfr[n][0] = *(const short8*)(Bs_s + boff0 + (2 + n) * 1024);
            bfr[n][1] = *(const short8*)(Bs_s + boff1 + (2 + n) * 1024);
        }
        if (st1) { gl_lds16(pb00, Bs_u + dj0); gl_lds16(pb01, Bs_u + dj1);
                   pb00 += 64; pb01 += 64; }
        __builtin_amdgcn_s_barrier();
        asm volatile("s_waitcnt lgkmcnt(0)" ::: "memory");
        __builtin_amdgcn_sched_barrier(0);
        __builtin_amdgcn_s_setprio(1);
        #pragma unroll
        for (int m = 0; m < 4; ++m)
            #pragma unroll
            for (int n = 0; n < 2; ++n) {
                acc[m][n + 2] = __builtin_amdgcn_mfma_f32_16x16x32_bf16(af[m][0], bfr[n][0], acc[m][n + 2], 0, 0, 0);
                acc[m][n + 2] = __builtin_amdgcn_mfma_f32_16x16x32_bf16(af[m][1], bfr[n][1], acc[m][n + 2], 0, 0, 0);
            }
        __builtin_amdgcn_s_setprio(0);
        __builtin_amdgcn_s_barrier();

        // ---- P2: read A m4-7 ; stage B-h1(t+1)
        #pragma unroll
        for (int m = 0; m < 4; ++m) {
            af[m][0] = *(const short8*)(As_s + aoff0 + (4 + m) * 1024);
            af[m][1] = *(const short8*)(As_s + aoff1 + (4 + m) * 1024);
        }
        if (st1) { gl_lds16(pb10, Bs_u + 8192 + dj0); gl_lds16(pb11, Bs_u + 8192 + dj1);
                   pb10 += 64; pb11 += 64; }
        __builtin_amdgcn_s_barrier();
        asm volatile("s_waitcnt lgkmcnt(0)" ::: "memory");
        __builtin_amdgcn_sched_barrier(0);
        __builtin_amdgcn_s_setprio(1);
        #pragma unroll
        for (int m = 0; m < 4; ++m)
            #pragma unroll
            for (int n = 0; n < 2; ++n) {
                acc[4 + m][n + 2] = __builtin_amdgcn_mfma_f32_16x16x32_bf16(af[m][0], bfr[n][0], acc[4 + m][n + 2], 0, 0, 0);
                acc[4 + m][n + 2] = __builtin_amdgcn_mfma_f32_16x16x32_bf16(af[m][1], bfr[n][1], acc[4 + m][n + 2], 0, 0, 0);
            }
        __builtin_amdgcn_s_setprio(0);
        __builtin_amdgcn_s_barrier();

        // ---- P3: read B n0-1 ; stage A-h0(t+2) -> slot s ; group close vmcnt(2)
        #pragma unroll
        for (int n = 0; n < 2; ++n) {
            bfr[n][0] = *(const short8*)(Bs_s + boff0 + n * 1024);
            bfr[n][1] = *(const short8*)(Bs_s + boff1 + n * 1024);
        }
        if (st2) { gl_lds16(pa00, As_s + dj0); gl_lds16(pa01, As_s + dj1);
                   pa00 += 64; pa01 += 64; }
        __builtin_amdgcn_s_barrier();
        asm volatile("s_waitcnt lgkmcnt(0)" ::: "memory");
        __builtin_amdgcn_sched_barrier(0);
        __builtin_amdgcn_s_setprio(1);
        #pragma unroll
        for (int m = 0; m < 4; ++m)
            #pragma unroll
            for (int n = 0; n < 2; ++n) {
                acc[4 + m][n] = __builtin_amdgcn_mfma_f32_16x16x32_bf16(af[m][0], bfr[n][0], acc[4 + m][n], 0, 0, 0);
                acc[4 + m][n] = __builtin_amdgcn_mfma_f32_16x16x32_bf16(af[m][1], bfr[n][1], acc[4 + m][n], 0, 0, 0);
            }
        __builtin_amdgcn_s_setprio(0);
        asm volatile("s_waitcnt vmcnt(2)" ::: "memory");
        __builtin_amdgcn_s_barrier();
    }

    // ---- epilogue: C write (rows guarded) + optional fused col-stats ----
    float cs[4] = {}, cq[4] = {};
    #pragma unroll
    for (int m = 0; m < 8; ++m) {
        #pragma unroll
        for (int rr = 0; rr < 4; ++rr) {
            int grow = row0 + wm * 128 + m * 16 + qq * 4 + rr;
            if (grow >= M) continue;
            #pragma unroll
            for (int n = 0; n < 4; ++n) {
                int gcol = col0 + wn * 64 + n * 16 + ml;
                float v = acc[m][n][rr];
                if (BIAS) v += bias[gcol];
                size_t idx = (size_t)grow * CN + gcol;
                if (ACC) v += ldacc(&C[idx]);
                if (STATS) { cs[n] += v; cq[n] += v * v; }
                stv(&C[idx], v);
            }
        }
    }
    if (STATS) {
        #pragma unroll
        for (int n = 0; n < 4; ++n) {
            float s = cs[n];
            s += __shfl_xor(s, 16); s += __shfl_xor(s, 32);
            float q2 = cq[n];
            q2 += __shfl_xor(q2, 16); q2 += __shfl_xor(q2, 32);
            if (lane < 16) {
                int gcol = col0 + wn * 64 + n * 16 + ml;
                atomicAdd(&sumv[gcol], s);
                atomicAdd(&ssv[gcol], q2);
            }
        }
    }
}

// ---- BN prep: per-column scale/shift from fused stats ----
__global__ void k_bnprep(const float* __restrict__ sum, const float* __restrict__ ss,
                         const float* __restrict__ gamma, const float* __restrict__ beta,
                         float* __restrict__ scale, float* __restrict__ shift, int C) {
    int c = blockIdx.x * blockDim.x + threadIdx.x;
    if (c >= C) return;
    const float invN = 1.0f / (float)N_NODES;
    float mu = sum[c] * invN;
    float var = ss[c] * invN - mu * mu;
    float sc = rsqrtf(fmaxf(var, 0.f) + BN_EPS) * gamma[c];
    scale[c] = sc;
    shift[c] = beta[c] - mu * sc;
}

// ---- BatchNorm + LeakyReLU, bf16 in place, short8 vectorized ----
template<int C>
__global__ void k_bn8(u16* __restrict__ h, const float* __restrict__ scale,
                      const float* __restrict__ shift) {
    long long t = (long long)blockIdx.x * blockDim.x + threadIdx.x;
    if (t >= (long long)N_NODES * C / 8) return;
    long long base = t << 3;
    int c0 = (int)(base & (C - 1));
    short8 v = *(const short8*)&h[base];
    short8 o;
    #pragma unroll
    for (int k = 0; k < 8; ++k) {
        float y = b2f((u16)v[k]) * scale[c0 + k] + shift[c0 + k];
        o[k] = (short)f2bs(y > 0.f ? y : ALPHA * y);
    }
    *(short8*)&h[base] = o;
}

extern "C" void kernel_launch(void* const* d_in, const int* in_sizes, int n_in,
                              void* d_out, int out_size, void* d_ws, size_t ws_size,
                              hipStream_t stream) {
    const float* x      = (const float*)d_in[0];
    const int*   ei     = (const int*)d_in[1];
    const int*   ety    = (const int*)d_in[2];
    const float* basis1 = (const float*)d_in[3];
    const float* comp1  = (const float*)d_in[4];
    const float* root1  = (const float*)d_in[5];
    const float* bias1  = (const float*)d_in[6];
    const float* gamma1 = (const float*)d_in[7];
    const float* beta1  = (const float*)d_in[8];
    const float* basis2 = (const float*)d_in[9];
    const float* comp2  = (const float*)d_in[10];
    const float* root2  = (const float*)d_in[11];
    const float* bias2  = (const float*)d_in[12];
    const float* gamma2 = (const float*)d_in[13];
    const float* beta2  = (const float*)d_in[14];
    const float* Wf     = (const float*)d_in[15];
    const float* bf_    = (const float*)d_in[16];
    const int* src = ei;
    const int* tgt = ei + N_EDGES;

    // opt-in to 128 KB dynamic LDS for the GEMM instantiations (idempotent)
    static bool attr_done = false;
    if (!attr_done) {
        hipFuncSetAttribute((const void*)k_mgemm<C2, u16, false, true, true>,
                            hipFuncAttributeMaxDynamicSharedMemorySize, 131072);
        hipFuncSetAttribute((const void*)k_mgemm<C3, u16, false, true, false>,
                            hipFuncAttributeMaxDynamicSharedMemorySize, 131072);
        hipFuncSetAttribute((const void*)k_mgemm<C3, u16, true, false, true>,
                            hipFuncAttributeMaxDynamicSharedMemorySize, 131072);
        hipFuncSetAttribute((const void*)k_mgemm<C3, float, false, true, false>,
                            hipFuncAttributeMaxDynamicSharedMemorySize, 131072);
        attr_done = true;
    }

    // ---- workspace layout (~203 MB) ----
    const int nscanb = (NR + 255) / 256;    // 1563
    char* p = (char*)d_ws;
    auto alloc = [&](size_t bytes) { void* r = (void*)p; p += (bytes + 63) & ~63ULL; return r; };
    u16* regionA = (u16*)alloc((size_t)N_NODES * XSTRIDE * 2);  // 102.4 MB
    u16* h1bf    = (u16*)alloc((size_t)N_NODES * C2 * 2);       // 25.6 MB
    u16* h2bf    = (u16*)alloc((size_t)N_NODES * C3 * 2);       // 51.2 MB
    u16* xbf     = (u16*)alloc((size_t)N_NODES * C1 * 2);       // 12.8 MB
    int* cnt     = (int*)alloc((size_t)NR * 4);
    int* off     = (int*)alloc((size_t)(NR + 1) * 4);
    int* cursor  = (int*)alloc((size_t)NR * 4);
    int* esrc    = (int*)alloc((size_t)N_EDGES * 4);
    int* bsum    = (int*)alloc((size_t)nscanb * 4);
    u16* Bt1     = (u16*)alloc((size_t)C2 * 1152 * 2);
    u16* Bt2     = (u16*)alloc((size_t)C3 * 2304 * 2);
    u16* Btf     = (u16*)alloc((size_t)C3 * C3 * 2);
    float* stats = (float*)alloc(3072 * 4);
    float* sum1 = stats, *ss1 = stats + 256, *sum2 = stats + 512, *ss2 = stats + 1024;
    float* sc1 = stats + 1536, *sh1 = stats + 1792;
    float* sc2 = stats + 2048, *sh2 = stats + 2560;

    hipMemsetAsync(cnt, 0, (size_t)NR * 4, stream);
    hipMemsetAsync(stats, 0, 1536 * 4, stream);

    // weights + x->bf16 + CSR
    k_b1<<<cdivu((long long)C2 * 1152, 256), 256, 0, stream>>>(comp1, basis1, root1, Bt1);
    k_b2<<<cdivu((long long)C3 * 2304, 256), 256, 0, stream>>>(comp2, basis2, root2, Bt2);
    k_btf<<<cdivu((long long)C3 * C3, 256), 256, 0, stream>>>(Wf, Btf);
    k_f2b<<<cdivu((long long)N_NODES * C1, 256), 256, 0, stream>>>(x, xbf, (long long)N_NODES * C1);
    k_count<<<cdivu(N_EDGES, 256), 256, 0, stream>>>(tgt, ety, cnt);
    k_scan1<<<nscanb, 256, 0, stream>>>(cnt, off, bsum);
    k_scan2<<<1, 256, 0, stream>>>(bsum, nscanb);
    k_scan3<<<nscanb, 256, 0, stream>>>(off, bsum, cursor);
    k_fill<<<cdivu(N_EDGES, 256), 256, 0, stream>>>(src, tgt, ety, cursor, esrc);

    const unsigned gym = cdivu(N_NODES, 256);   // 196

    // ---- layer 1: A = [mean_r(x) x8 | x], K=1152 -> h1bf (stats fused) ----
    k_gather<C1, 8><<<cdivu((long long)N_NODES * 8, 4), 256, 0, stream>>>(off, esrc, xbf, regionA, 0);
    {
        dim3 g(C2 / 256, gym);
        k_mgemm<C2, u16, false, true, true><<<g, 512, 131072, stream>>>(
            regionA, XSTRIDE, 1024, xbf, C1, 1152, Bt1, 1152, bias1, h1bf, N_NODES, sum1, ss1);
    }
    k_bnprep<<<1, C2, 0, stream>>>(sum1, ss1, gamma1, beta1, sc1, sh1, C2);
    k_bn8<C2><<<cdivu((long long)N_NODES * C2 / 8, 256), 256, 0, stream>>>(h1bf, sc1, sh1);

    // ---- layer 2 (two K-halves): h2 = [mean r0..3]@W + bias, += [mean r4..7 | h1]@W ----
    {
        dim3 g(C3 / 256, gym);
        k_gather<C2, 4><<<cdivu((long long)N_NODES * 4, 4), 256, 0, stream>>>(off, esrc, h1bf, regionA, 0);
        k_mgemm<C3, u16, false, true, false><<<g, 512, 131072, stream>>>(
            regionA, XSTRIDE, 1024, (const u16*)nullptr, 0, 1024, Bt2, 2304, bias2, h2bf, N_NODES,
            nullptr, nullptr);
        k_gather<C2, 4><<<cdivu((long long)N_NODES * 4, 4), 256, 0, stream>>>(off, esrc, h1bf, regionA, 4);
        k_mgemm<C3, u16, true, false, true><<<g, 512, 131072, stream>>>(
            regionA, XSTRIDE, 1024, h1bf, C2, 1280, Bt2 + 1024, 2304, nullptr, h2bf, N_NODES,
            sum2, ss2);
    }
    k_bnprep<<<1, C3, 0, stream>>>(sum2, ss2, gamma2, beta2, sc2, sh2, C3);
    k_bn8<C3><<<cdivu((long long)N_NODES * C3 / 8, 256), 256, 0, stream>>>(h2bf, sc2, sh2);

    // ---- final linear -> fp32 out ----
    {
        dim3 g(C3 / 256, gym);
        k_mgemm<C3, float, false, true, false><<<g, 512, 131072, stream>>>(
            h2bf, C3, 512, (const u16*)nullptr, 0, 512, Btf, C3, bf_, (float*)d_out, N_NODES,
            nullptr, nullptr);
    }
}

// Round 11
// 777.989 us; speedup vs baseline: 2.0016x; 1.0132x over previous
//
#include <hip/hip_runtime.h>
#include <hip/hip_bf16.h>

#define N_NODES 50000
#define N_EDGES 800000
#define R 8
#define NB 30
#define C1 128
#define C2 256
#define C3 512
#define NR (N_NODES * R)
#define BN_EPS 1e-5f
#define ALPHA 0.01f
#define XSTRIDE 1024          // regionA row stride (bf16 elems), both layers

typedef unsigned short u16;
typedef __attribute__((ext_vector_type(8))) short short8;
typedef __attribute__((ext_vector_type(4))) float floatx4;

static inline unsigned cdivu(long long a, long long b) { return (unsigned)((a + b - 1) / b); }

__device__ __forceinline__ u16 f2bs(float f) {
    __hip_bfloat16 h = __float2bfloat16(f);
    return *reinterpret_cast<u16*>(&h);
}
__device__ __forceinline__ float b2f(u16 u) {
    return __uint_as_float(((unsigned)u) << 16);
}
__device__ __forceinline__ float ldacc(const float* p) { return *p; }
__device__ __forceinline__ float ldacc(const u16* p) { return b2f(*p); }
__device__ __forceinline__ void stv(float* p, float v) { *p = v; }
__device__ __forceinline__ void stv(u16* p, float v) { *p = f2bs(v); }

// async global->LDS, 16B per lane; LDS dest is wave-uniform base + lane*16
__device__ __forceinline__ void gl_lds16(const u16* g, u16* l) {
    __builtin_amdgcn_global_load_lds(
        (const __attribute__((address_space(1))) void*)g,
        (__attribute__((address_space(3))) void*)l, 16, 0, 0);
}

// ---- weight builders: Bt[o][k] bf16, k = [rel-blocks | root] ----
__global__ void k_b1(const float* __restrict__ comp, const float* __restrict__ basis,
                     const float* __restrict__ root, u16* __restrict__ Bt) {
    int t = blockIdx.x * blockDim.x + threadIdx.x;
    if (t >= C2 * 1152) return;
    int o = t % C2, k = t / C2;         // coalesced basis/root reads over o
    float v;
    if (k < R * C1) {
        int r = k >> 7, i = k & 127;
        v = 0.f;
        for (int b = 0; b < NB; ++b)
            v += comp[r * NB + b] * basis[((size_t)b * C1 + i) * C2 + o];
    } else v = root[(size_t)(k - R * C1) * C2 + o];
    Bt[(size_t)o * 1152 + k] = f2bs(v);
}
__global__ void k_b2(const float* __restrict__ comp, const float* __restrict__ basis,
                     const float* __restrict__ root, u16* __restrict__ Bt) {
    int t = blockIdx.x * blockDim.x + threadIdx.x;
    if (t >= C3 * 2304) return;
    int o = t % C3, k = t / C3;
    float v;
    if (k < R * C2) {
        int r = k >> 8, i = k & 255;
        v = 0.f;
        for (int b = 0; b < NB; ++b)
            v += comp[r * NB + b] * basis[((size_t)b * C2 + i) * C3 + o];
    } else v = root[(size_t)(k - R * C2) * C3 + o];
    Bt[(size_t)o * 2304 + k] = f2bs(v);
}
__global__ void k_btf(const float* __restrict__ Wf, u16* __restrict__ Bt) {
    int t = blockIdx.x * blockDim.x + threadIdx.x;
    if (t >= C3 * C3) return;
    int o = t % C3, k = t / C3;
    Bt[(size_t)o * C3 + k] = f2bs(Wf[(size_t)k * C3 + o]);
}

// ---- x fp32 -> bf16 ----
__global__ void k_f2b(const float* __restrict__ s, u16* __restrict__ d, long long n) {
    long long t = (long long)blockIdx.x * blockDim.x + threadIdx.x;
    if (t < n) d[t] = f2bs(s[t]);
}

// ---- CSR build ----
__global__ void k_count(const int* __restrict__ tgt, const int* __restrict__ ety,
                        int* __restrict__ cnt) {
    int e = blockIdx.x * blockDim.x + threadIdx.x;
    if (e >= N_EDGES) return;
    atomicAdd(&cnt[tgt[e] * R + ety[e]], 1);
}
__global__ void k_scan1(const int* __restrict__ cnt, int* __restrict__ off,
                        int* __restrict__ bsum) {
    __shared__ int s[256];
    int tid = threadIdx.x;
    int i = blockIdx.x * 256 + tid;
    int v = (i < NR) ? cnt[i] : 0;
    s[tid] = v;
    __syncthreads();
    for (int o = 1; o < 256; o <<= 1) {
        int x = (tid >= o) ? s[tid - o] : 0;
        __syncthreads();
        s[tid] += x;
        __syncthreads();
    }
    if (i < NR) off[i] = s[tid] - v;            // exclusive within block
    if (tid == 255) bsum[blockIdx.x] = s[255];
}
__global__ void k_scan2(int* __restrict__ bsum, int nb) {
    __shared__ int s[256];
    __shared__ int carry_s;
    int tid = threadIdx.x;
    if (tid == 0) carry_s = 0;
    __syncthreads();
    for (int base = 0; base < nb; base += 256) {
        int i = base + tid;
        int v = (i < nb) ? bsum[i] : 0;
        s[tid] = v;
        __syncthreads();
        for (int o = 1; o < 256; o <<= 1) {
            int x = (tid >= o) ? s[tid - o] : 0;
            __syncthreads();
            s[tid] += x;
            __syncthreads();
        }
        int carry = carry_s;
        if (i < nb) bsum[i] = s[tid] - v + carry;
        int tot = s[255];
        __syncthreads();
        if (tid == 0) carry_s = carry + tot;
        __syncthreads();
    }
}
__global__ void k_scan3(int* __restrict__ off, const int* __restrict__ bsum,
                        int* __restrict__ cursor) {
    int i = blockIdx.x * 256 + threadIdx.x;
    if (i < NR) {
        int v = off[i] + bsum[blockIdx.x];
        off[i] = v;
        cursor[i] = v;
    }
    if (i == 0) off[NR] = N_EDGES;
}
__global__ void k_fill(const int* __restrict__ src, const int* __restrict__ tgt,
                       const int* __restrict__ ety, int* __restrict__ cursor,
                       int* __restrict__ esrc) {
    int e = blockIdx.x * blockDim.x + threadIdx.x;
    if (e >= N_EDGES) return;
    int pos = atomicAdd(&cursor[tgt[e] * R + ety[e]], 1);
    esrc[pos] = src[e];
}

// ---- gather: mean of src rows per (tgt, rel), bf16 in/out, no atomics ----
// Subwave-per-edge: wave per (t, rr) segment; LPR = CIN/8 lanes load one full
// row as short8 (16B/lane), NSW = 64/LPR subwaves each handle a different
// edge concurrently. Cross-subwave combine: shfl_xor tree; subwave 0 writes.
// NOTE (R9 lesson): do NOT fuse this into the GEMM — per-lane scattered 16B
// reads + CSR chains inside the barrier-locked phases collapsed BW to 400GB/s.
template<int CIN, int NREL>
__global__ void k_gather(const int* __restrict__ off, const int* __restrict__ esrc,
                         const u16* __restrict__ srcbf, u16* __restrict__ Xbar, int r0) {
    constexpr int LPR = CIN / 8;        // lanes per row: 16 (C1) or 32 (C2)
    constexpr int NSW = 64 / LPR;       // subwaves: 4 or 2
    int wid = blockIdx.x * 4 + (threadIdx.x >> 6);
    if (wid >= N_NODES * NREL) return;
    int lane = threadIdx.x & 63;
    int sw = lane / LPR, l = lane & (LPR - 1);
    int t = wid / NREL, rr = wid - t * NREL;
    int b = t * R + r0 + rr;
    int o0 = off[b], o1 = off[b + 1];
    float acc[8] = {};
    for (int j = o0; j < o1; j += NSW) {
        int e = j + sw;
        if (e < o1) {
            int s = esrc[e];
            short8 v = *(const short8*)&srcbf[(size_t)s * CIN + l * 8];
            #pragma unroll
            for (int k = 0; k < 8; ++k) acc[k] += b2f((u16)v[k]);
        }
    }
    #pragma unroll
    for (int m = LPR; m < 64; m <<= 1)
        #pragma unroll
        for (int k = 0; k < 8; ++k) acc[k] += __shfl_xor(acc[k], m);
    int deg = o1 - o0;
    float w = (deg > 0) ? 1.f / (float)deg : 0.f;
    if (sw == 0) {
        short8 ov;
        #pragma unroll
        for (int k = 0; k < 8; ++k) ov[k] = (short)f2bs(acc[k] * w);
        *(short8*)&Xbar[(size_t)t * XSTRIDE + rr * CIN + l * 8] = ov;
    }
}

// ---- MFMA bf16 GEMM, 256x256 schedule, 4 barriers/K-tile ----
// C[M,CN] (+)= [A0|A1](bf16) @ Bt^T (+ bias), optional fused col-stats.
// BM=BN=256, BK=64; 8 waves (2M x 4N), wave tile 128x64; 128 KB dynamic LDS.
// Per K-tile: 4 phases, each {ds_reads ; 1 half-tile gl_lds prefetch ;
// lgkmcnt(0)+sched_barrier(0) ; setprio(1) ; 16 MFMA ; setprio(0) ;
// [P3: vmcnt(2)] ; s_barrier}.  (R11: the pre-MFMA barrier was pure lockstep
// — deleted. Hazard audit: (1) staged-data-lands-before-read is enforced by
// the tile-close vmcnt(2)+barrier [unchanged, R7-proven: in-order queue at
// t-close = Ah1,Bh0,Bh1,Ah0 -> vmcnt(2) leaves only Ah0(t+2) in flight];
// (2) reads-drain-before-overwrite: A-h0(t+2) is issued at P3, >=1 full
// lgkmcnt(0)+phase-end-barrier after its last readers (P0 m0-3, P2 m4-7);
// all other stages target the opposite LDS slot. Wave skew bounded <=1 phase
// by the retained phase-end barriers.)
// Chunk-XOR LDS swizzle (both-sides, rule #21) + bijective XCD swizzle (m204).
// STATS: epilogue accumulates per-column sum/ssq of final v (fused colstats).
template<int CN, typename OT, bool ACC, bool BIAS, bool STATS>
__global__ __launch_bounds__(512, 2) void k_mgemm(
        const u16* __restrict__ A0, int sA0, int Ksplit,
        const u16* __restrict__ A1, int sA1, int Ktot,
        const u16* __restrict__ Bt, int sB,
        const float* __restrict__ bias, OT* __restrict__ C, int M,
        float* __restrict__ sumv, float* __restrict__ ssv) {
    extern __shared__ u16 lds[];
    u16* const Asl = lds;                 // 2 slots x 16384 elems (rows x 64)
    u16* const Bsl = lds + 32768;         // 2 slots x 16384

    const int tid = threadIdx.x;
    const int lane = tid & 63, w = tid >> 6;
    const int wm = w >> 2, wn = w & 3;            // 2M x 4N wave grid
    const int ml = lane & 15, qq = lane >> 4;
    const int ml7 = ml & 7;
    const int p0 = qq ^ ml7;
    const int p1 = (4 + qq) ^ ml7;
    const int aoff0 = (wm * 128 + ml) * 64 + p0 * 8;
    const int aoff1 = (wm * 128 + ml) * 64 + p1 * 8;
    const int boff0 = (wn * 64 + ml) * 64 + p0 * 8;
    const int boff1 = (wn * 64 + ml) * 64 + p1 * 8;

    // bijective XCD-aware swizzle on the linear block id
    const int nbx = gridDim.x;
    const int nwg = nbx * (int)gridDim.y;
    const int orig = blockIdx.y * nbx + blockIdx.x;
    const int qc = nwg >> 3, rc = nwg & 7;
    const int xcd = orig & 7, lin = orig >> 3;
    const int wgid = (xcd < rc ? xcd * (qc + 1) : rc * (qc + 1) + (xcd - rc) * qc) + lin;
    const int col0 = (wgid % nbx) * 256;
    const int row0 = (wgid / nbx) * 256;

    // staging geometry: each wave covers rows (2w+j)*8 .. +7 of a 128-row half
    const int l8 = lane >> 3;
    const int csrc = ((lane & 7) ^ l8) * 8;       // pre-swizzled source chunk
    const int rj0 = (2 * w + 0) * 8 + l8;
    const int rj1 = (2 * w + 1) * 8 + l8;
    const u16* A1g = A1 ? A1 : A0;
    const int  sA1g = A1 ? sA1 : sA0;
    int ga00 = row0 + rj0;        if (ga00 >= M) ga00 = M - 1;
    int ga01 = row0 + rj1;        if (ga01 >= M) ga01 = M - 1;
    int ga10 = row0 + 128 + rj0;  if (ga10 >= M) ga10 = M - 1;
    int ga11 = row0 + 128 + rj1;  if (ga11 >= M) ga11 = M - 1;
    const u16* pa00 = A0 + (size_t)ga00 * sA0 + csrc;   // A-h0 streams
    const u16* pa01 = A0 + (size_t)ga01 * sA0 + csrc;
    const u16* pa10 = A0 + (size_t)ga10 * sA0 + csrc;   // A-h1 streams
    const u16* pa11 = A0 + (size_t)ga11 * sA0 + csrc;
    const u16* ta00 = A1g + (size_t)ga00 * sA1g + csrc; // seg-1 bases
    const u16* ta01 = A1g + (size_t)ga01 * sA1g + csrc;
    const u16* ta10 = A1g + (size_t)ga10 * sA1g + csrc;
    const u16* ta11 = A1g + (size_t)ga11 * sA1g + csrc;
    const u16* pb00 = Bt + (size_t)(col0 + rj0) * sB + csrc;        // B-h0
    const u16* pb01 = Bt + (size_t)(col0 + rj1) * sB + csrc;
    const u16* pb10 = Bt + (size_t)(col0 + 128 + rj0) * sB + csrc;  // B-h1
    const u16* pb11 = Bt + (size_t)(col0 + 128 + rj1) * sB + csrc;

    const int dj0 = (2 * w + 0) * 512;    // LDS dest elem offset within half
    const int dj1 = (2 * w + 1) * 512;

    const int NT = Ktot >> 6;
    const int ks64 = Ksplit >> 6;

    // prologue: tile0 (A h0,h1; B h0,h1) -> slot0 ; A-h0 of tile1 -> slot1
    gl_lds16(pa00, Asl + dj0);          gl_lds16(pa01, Asl + dj1);          pa00 += 64; pa01 += 64;
    gl_lds16(pa10, Asl + 8192 + dj0);   gl_lds16(pa11, Asl + 8192 + dj1);   pa10 += 64; pa11 += 64;
    gl_lds16(pb00, Bsl + dj0);          gl_lds16(pb01, Bsl + dj1);          pb00 += 64; pb01 += 64;
    gl_lds16(pb10, Bsl + 8192 + dj0);   gl_lds16(pb11, Bsl + 8192 + dj1);   pb10 += 64; pb11 += 64;
    gl_lds16(pa00, Asl + 16384 + dj0);  gl_lds16(pa01, Asl + 16384 + dj1);  pa00 += 64; pa01 += 64;
    asm volatile("s_waitcnt vmcnt(2)" ::: "memory");
    __builtin_amdgcn_s_barrier();

    floatx4 acc[8][4] = {};
    short8 af[4][2], bfr[2][2];

    for (int t = 0; t < NT; ++t) {
        const int s = t & 1;
        u16* const As_s = Asl + s * 16384;
        u16* const Bs_s = Bsl + s * 16384;
        u16* const As_u = Asl + (s ^ 1) * 16384;
        u16* const Bs_u = Bsl + (s ^ 1) * 16384;
        if (t == ks64 - 1) { pa10 = ta10; pa11 = ta11; }
        if (t == ks64 - 2) { pa00 = ta00; pa01 = ta01; }
        const bool st1 = (t + 1 < NT), st2 = (t + 2 < NT);

        // ---- P0: read A m0-3 + B n0-1 ; stage A-h1(t+1) -> slot u
        #pragma unroll
        for (int m = 0; m < 4; ++m) {
            af[m][0] = *(const short8*)(As_s + aoff0 + m * 1024);
            af[m][1] = *(const short8*)(As_s + aoff1 + m * 1024);
        }
        #pragma unroll
        for (int n = 0; n < 2; ++n) {
            bfr[n][0] = *(const short8*)(Bs_s + boff0 + n * 1024);
            bfr[n][1] = *(const short8*)(Bs_s + boff1 + n * 1024);
        }
        if (st1) { gl_lds16(pa10, As_u + 8192 + dj0); gl_lds16(pa11, As_u + 8192 + dj1);
                   pa10 += 64; pa11 += 64; }
        asm volatile("s_waitcnt lgkmcnt(0)" ::: "memory");
        __builtin_amdgcn_sched_barrier(0);
        __builtin_amdgcn_s_setprio(1);
        #pragma unroll
        for (int m = 0; m < 4; ++m)
            #pragma unroll
            for (int n = 0; n < 2; ++n) {
                acc[m][n] = __builtin_amdgcn_mfma_f32_16x16x32_bf16(af[m][0], bfr[n][0], acc[m][n], 0, 0, 0);
                acc[m][n] = __builtin_amdgcn_mfma_f32_16x16x32_bf16(af[m][1], bfr[n][1], acc[m][n], 0, 0, 0);
            }
        __builtin_amdgcn_s_setprio(0);
        __builtin_amdgcn_s_barrier();

        // ---- P1: read B n2-3 ; stage B-h0(t+1)
        #pragma unroll
        for (int n = 0; n < 2; ++n) {
            bfr[n][0] = *(const short8*)(Bs_s + boff0 + (2 + n) * 1024);
            bfr[n][1] = *(const short8*)(Bs_s + boff1 + (2 + n) * 1024);
        }
        if (st1) { gl_lds16(pb00, Bs_u + dj0); gl_lds16(pb01, Bs_u + dj1);
                   pb00 += 64; pb01 += 64; }
        asm volatile("s_waitcnt lgkmcnt(0)" ::: "memory");
        __builtin_amdgcn_sched_barrier(0);
        __builtin_amdgcn_s_setprio(1);
        #pragma unroll
        for (int m = 0; m < 4; ++m)
            #pragma unroll
            for (int n = 0; n < 2; ++n) {
                acc[m][n + 2] = __builtin_amdgcn_mfma_f32_16x16x32_bf16(af[m][0], bfr[n][0], acc[m][n + 2], 0, 0, 0);
                acc[m][n + 2] = __builtin_amdgcn_mfma_f32_16x16x32_bf16(af[m][1], bfr[n][1], acc[m][n + 2], 0, 0, 0);
            }
        __builtin_amdgcn_s_setprio(0);
        __builtin_amdgcn_s_barrier();

        // ---- P2: read A m4-7 ; stage B-h1(t+1)
        #pragma unroll
        for (int m = 0; m < 4; ++m) {
            af[m][0] = *(const short8*)(As_s + aoff0 + (4 + m) * 1024);
            af[m][1] = *(const short8*)(As_s + aoff1 + (4 + m) * 1024);
        }
        if (st1) { gl_lds16(pb10, Bs_u + 8192 + dj0); gl_lds16(pb11, Bs_u + 8192 + dj1);
                   pb10 += 64; pb11 += 64; }
        asm volatile("s_waitcnt lgkmcnt(0)" ::: "memory");
        __builtin_amdgcn_sched_barrier(0);
        __builtin_amdgcn_s_setprio(1);
        #pragma unroll
        for (int m = 0; m < 4; ++m)
            #pragma unroll
            for (int n = 0; n < 2; ++n) {
                acc[4 + m][n + 2] = __builtin_amdgcn_mfma_f32_16x16x32_bf16(af[m][0], bfr[n][0], acc[4 + m][n + 2], 0, 0, 0);
                acc[4 + m][n + 2] = __builtin_amdgcn_mfma_f32_16x16x32_bf16(af[m][1], bfr[n][1], acc[4 + m][n + 2], 0, 0, 0);
            }
        __builtin_amdgcn_s_setprio(0);
        __builtin_amdgcn_s_barrier();

        // ---- P3: read B n0-1 ; stage A-h0(t+2) -> slot s ; tile close vmcnt(2)
        #pragma unroll
        for (int n = 0; n < 2; ++n) {
            bfr[n][0] = *(const short8*)(Bs_s + boff0 + n * 1024);
            bfr[n][1] = *(const short8*)(Bs_s + boff1 + n * 1024);
        }
        if (st2) { gl_lds16(pa00, As_s + dj0); gl_lds16(pa01, As_s + dj1);
                   pa00 += 64; pa01 += 64; }
        asm volatile("s_waitcnt lgkmcnt(0)" ::: "memory");
        __builtin_amdgcn_sched_barrier(0);
        __builtin_amdgcn_s_setprio(1);
        #pragma unroll
        for (int m = 0; m < 4; ++m)
            #pragma unroll
            for (int n = 0; n < 2; ++n) {
                acc[4 + m][n] = __builtin_amdgcn_mfma_f32_16x16x32_bf16(af[m][0], bfr[n][0], acc[4 + m][n], 0, 0, 0);
                acc[4 + m][n] = __builtin_amdgcn_mfma_f32_16x16x32_bf16(af[m][1], bfr[n][1], acc[4 + m][n], 0, 0, 0);
            }
        __builtin_amdgcn_s_setprio(0);
        asm volatile("s_waitcnt vmcnt(2)" ::: "memory");
        __builtin_amdgcn_s_barrier();
    }

    // ---- epilogue: C write (rows guarded) + optional fused col-stats ----
    float cs[4] = {}, cq[4] = {};
    #pragma unroll
    for (int m = 0; m < 8; ++m) {
        #pragma unroll
        for (int rr = 0; rr < 4; ++rr) {
            int grow = row0 + wm * 128 + m * 16 + qq * 4 + rr;
            if (grow >= M) continue;
            #pragma unroll
            for (int n = 0; n < 4; ++n) {
                int gcol = col0 + wn * 64 + n * 16 + ml;
                float v = acc[m][n][rr];
                if (BIAS) v += bias[gcol];
                size_t idx = (size_t)grow * CN + gcol;
                if (ACC) v += ldacc(&C[idx]);
                if (STATS) { cs[n] += v; cq[n] += v * v; }
                stv(&C[idx], v);
            }
        }
    }
    if (STATS) {
        #pragma unroll
        for (int n = 0; n < 4; ++n) {
            float s = cs[n];
            s += __shfl_xor(s, 16); s += __shfl_xor(s, 32);
            float q2 = cq[n];
            q2 += __shfl_xor(q2, 16); q2 += __shfl_xor(q2, 32);
            if (lane < 16) {
                int gcol = col0 + wn * 64 + n * 16 + ml;
                atomicAdd(&sumv[gcol], s);
                atomicAdd(&ssv[gcol], q2);
            }
        }
    }
}

// ---- BN prep: per-column scale/shift from fused stats ----
__global__ void k_bnprep(const float* __restrict__ sum, const float* __restrict__ ss,
                         const float* __restrict__ gamma, const float* __restrict__ beta,
                         float* __restrict__ scale, float* __restrict__ shift, int C) {
    int c = blockIdx.x * blockDim.x + threadIdx.x;
    if (c >= C) return;
    const float invN = 1.0f / (float)N_NODES;
    float mu = sum[c] * invN;
    float var = ss[c] * invN - mu * mu;
    float sc = rsqrtf(fmaxf(var, 0.f) + BN_EPS) * gamma[c];
    scale[c] = sc;
    shift[c] = beta[c] - mu * sc;
}

// ---- BatchNorm + LeakyReLU, bf16 in place, short8 vectorized ----
template<int C>
__global__ void k_bn8(u16* __restrict__ h, const float* __restrict__ scale,
                      const float* __restrict__ shift) {
    long long t = (long long)blockIdx.x * blockDim.x + threadIdx.x;
    if (t >= (long long)N_NODES * C / 8) return;
    long long base = t << 3;
    int c0 = (int)(base & (C - 1));
    short8 v = *(const short8*)&h[base];
    short8 o;
    #pragma unroll
    for (int k = 0; k < 8; ++k) {
        float y = b2f((u16)v[k]) * scale[c0 + k] + shift[c0 + k];
        o[k] = (short)f2bs(y > 0.f ? y : ALPHA * y);
    }
    *(short8*)&h[base] = o;
}

extern "C" void kernel_launch(void* const* d_in, const int* in_sizes, int n_in,
                              void* d_out, int out_size, void* d_ws, size_t ws_size,
                              hipStream_t stream) {
    const float* x      = (const float*)d_in[0];
    const int*   ei     = (const int*)d_in[1];
    const int*   ety    = (const int*)d_in[2];
    const float* basis1 = (const float*)d_in[3];
    const float* comp1  = (const float*)d_in[4];
    const float* root1  = (const float*)d_in[5];
    const float* bias1  = (const float*)d_in[6];
    const float* gamma1 = (const float*)d_in[7];
    const float* beta1  = (const float*)d_in[8];
    const float* basis2 = (const float*)d_in[9];
    const float* comp2  = (const float*)d_in[10];
    const float* root2  = (const float*)d_in[11];
    const float* bias2  = (const float*)d_in[12];
    const float* gamma2 = (const float*)d_in[13];
    const float* beta2  = (const float*)d_in[14];
    const float* Wf     = (const float*)d_in[15];
    const float* bf_    = (const float*)d_in[16];
    const int* src = ei;
    const int* tgt = ei + N_EDGES;

    // opt-in to 128 KB dynamic LDS for the GEMM instantiations (idempotent)
    static bool attr_done = false;
    if (!attr_done) {
        hipFuncSetAttribute((const void*)k_mgemm<C2, u16, false, true, true>,
                            hipFuncAttributeMaxDynamicSharedMemorySize, 131072);
        hipFuncSetAttribute((const void*)k_mgemm<C3, u16, false, true, false>,
                            hipFuncAttributeMaxDynamicSharedMemorySize, 131072);
        hipFuncSetAttribute((const void*)k_mgemm<C3, u16, true, false, true>,
                            hipFuncAttributeMaxDynamicSharedMemorySize, 131072);
        hipFuncSetAttribute((const void*)k_mgemm<C3, float, false, true, false>,
                            hipFuncAttributeMaxDynamicSharedMemorySize, 131072);
        attr_done = true;
    }

    // ---- workspace layout (~203 MB) ----
    const int nscanb = (NR + 255) / 256;    // 1563
    char* p = (char*)d_ws;
    auto alloc = [&](size_t bytes) { void* r = (void*)p; p += (bytes + 63) & ~63ULL; return r; };
    u16* regionA = (u16*)alloc((size_t)N_NODES * XSTRIDE * 2);  // 102.4 MB
    u16* h1bf    = (u16*)alloc((size_t)N_NODES * C2 * 2);       // 25.6 MB
    u16* h2bf    = (u16*)alloc((size_t)N_NODES * C3 * 2);       // 51.2 MB
    u16* xbf     = (u16*)alloc((size_t)N_NODES * C1 * 2);       // 12.8 MB
    int* cnt     = (int*)alloc((size_t)NR * 4);
    int* off     = (int*)alloc((size_t)(NR + 1) * 4);
    int* cursor  = (int*)alloc((size_t)NR * 4);
    int* esrc    = (int*)alloc((size_t)N_EDGES * 4);
    int* bsum    = (int*)alloc((size_t)nscanb * 4);
    u16* Bt1     = (u16*)alloc((size_t)C2 * 1152 * 2);
    u16* Bt2     = (u16*)alloc((size_t)C3 * 2304 * 2);
    u16* Btf     = (u16*)alloc((size_t)C3 * C3 * 2);
    float* stats = (float*)alloc(3072 * 4);
    float* sum1 = stats, *ss1 = stats + 256, *sum2 = stats + 512, *ss2 = stats + 1024;
    float* sc1 = stats + 1536, *sh1 = stats + 1792;
    float* sc2 = stats + 2048, *sh2 = stats + 2560;

    hipMemsetAsync(cnt, 0, (size_t)NR * 4, stream);
    hipMemsetAsync(stats, 0, 1536 * 4, stream);

    // weights + x->bf16 + CSR
    k_b1<<<cdivu((long long)C2 * 1152, 256), 256, 0, stream>>>(comp1, basis1, root1, Bt1);
    k_b2<<<cdivu((long long)C3 * 2304, 256), 256, 0, stream>>>(comp2, basis2, root2, Bt2);
    k_btf<<<cdivu((long long)C3 * C3, 256), 256, 0, stream>>>(Wf, Btf);
    k_f2b<<<cdivu((long long)N_NODES * C1, 256), 256, 0, stream>>>(x, xbf, (long long)N_NODES * C1);
    k_count<<<cdivu(N_EDGES, 256), 256, 0, stream>>>(tgt, ety, cnt);
    k_scan1<<<nscanb, 256, 0, stream>>>(cnt, off, bsum);
    k_scan2<<<1, 256, 0, stream>>>(bsum, nscanb);
    k_scan3<<<nscanb, 256, 0, stream>>>(off, bsum, cursor);
    k_fill<<<cdivu(N_EDGES, 256), 256, 0, stream>>>(src, tgt, ety, cursor, esrc);

    const unsigned gym = cdivu(N_NODES, 256);   // 196

    // ---- layer 1: A = [mean_r(x) x8 | x], K=1152 -> h1bf (stats fused) ----
    k_gather<C1, 8><<<cdivu((long long)N_NODES * 8, 4), 256, 0, stream>>>(off, esrc, xbf, regionA, 0);
    {
        dim3 g(C2 / 256, gym);
        k_mgemm<C2, u16, false, true, true><<<g, 512, 131072, stream>>>(
            regionA, XSTRIDE, 1024, xbf, C1, 1152, Bt1, 1152, bias1, h1bf, N_NODES, sum1, ss1);
    }
    k_bnprep<<<1, C2, 0, stream>>>(sum1, ss1, gamma1, beta1, sc1, sh1, C2);
    k_bn8<C2><<<cdivu((long long)N_NODES * C2 / 8, 256), 256, 0, stream>>>(h1bf, sc1, sh1);

    // ---- layer 2 (two K-halves): h2 = [mean r0..3]@W + bias, += [mean r4..7 | h1]@W ----
    {
        dim3 g(C3 / 256, gym);
        k_gather<C2, 4><<<cdivu((long long)N_NODES * 4, 4), 256, 0, stream>>>(off, esrc, h1bf, regionA, 0);
        k_mgemm<C3, u16, false, true, false><<<g, 512, 131072, stream>>>(
            regionA, XSTRIDE, 1024, (const u16*)nullptr, 0, 1024, Bt2, 2304, bias2, h2bf, N_NODES,
            nullptr, nullptr);
        k_gather<C2, 4><<<cdivu((long long)N_NODES * 4, 4), 256, 0, stream>>>(off, esrc, h1bf, regionA, 4);
        k_mgemm<C3, u16, true, false, true><<<g, 512, 131072, stream>>>(
            regionA, XSTRIDE, 1024, h1bf, C2, 1280, Bt2 + 1024, 2304, nullptr, h2bf, N_NODES,
            sum2, ss2);
    }
    k_bnprep<<<1, C3, 0, stream>>>(sum2, ss2, gamma2, beta2, sc2, sh2, C3);
    k_bn8<C3><<<cdivu((long long)N_NODES * C3 / 8, 256), 256, 0, stream>>>(h2bf, sc2, sh2);

    // ---- final linear -> fp32 out ----
    {
        dim3 g(C3 / 256, gym);
        k_mgemm<C3, float, false, true, false><<<g, 512, 131072, stream>>>(
            h2bf, C3, 512, (const u16*)nullptr, 0, 512, Btf, C3, bf_, (float*)d_out, N_NODES,
            nullptr, nullptr);
    }
}